// Round 10
// baseline (721.944 us; speedup 1.0000x reference)
//
#include <hip/hip_runtime.h>
#include <stdint.h>

// Problem constants
#define NN    50000
#define EE    800000
#define IN_C  128
#define ED_C  64
#define HID_C 256
#define BB    128
#define KK    1000
#define G1_C  128
#define NV    50176   // NN padded to 196*256 for scan

// R6-R10: edge kernel ~160us floor = ea random-HBM reads at ~1.2TB/s.
// R11 fusions: 740->667. Accounting: edge 161 + budget ~140 for the rest
// => ~200us unexplained, likely launch gaps (14 dispatches) + mid kernels.
// R12 (this): collapse launches 15 -> 10, edge path untouched:
//  - k_h0 gone: gemm1 stages A = f2bs(agg+x) from f32 directly
//  - gmax+expsum+pool+head -> k_attn (1 block/segment, binary search, no atomics)
//  - scan3 folded into scatter (off[d]+aux[d>>8]); cnt reused as fill
//    (scan1 re-zeroes cnt after reading)

typedef __attribute__((ext_vector_type(8))) short bfrag;   // 8 x bf16
typedef __attribute__((ext_vector_type(4))) float f4acc;   // 4 x f32 acc

__device__ __forceinline__ unsigned short f2bs(float f){   // f32 -> bf16 (RNE)
  unsigned u = __float_as_uint(f);
  return (unsigned short)((u + 0x7fffu + ((u >> 16) & 1u)) >> 16);
}
__device__ __forceinline__ float bs2f(unsigned short s){
  return __uint_as_float(((unsigned)s) << 16);
}

// ------- setup: weights->bf16t, x->bf16, zero agg/cnt/aux ---------------
__global__ __launch_bounds__(256) void k_setup(
    const float* __restrict__ We, const float* __restrict__ W1,
    const float* __restrict__ W2, const float* __restrict__ Wg1,
    const float* __restrict__ x,
    unsigned short* __restrict__ Wet, unsigned short* __restrict__ W1t,
    unsigned short* __restrict__ W2t, unsigned short* __restrict__ Wg1t,
    unsigned short* __restrict__ xb,
    float* __restrict__ agg, int* __restrict__ cnt, int* __restrict__ aux)
{
  size_t i = (size_t)blockIdx.x * 256 + threadIdx.x;
  if (i < 128 * 64){ int c = (int)i >> 6, k = (int)i & 63;  Wet[i]  = f2bs(We[k * 128 + c]); }
  if (i < 256 * 128){ int n = (int)i >> 7, k = (int)i & 127; W1t[i]  = f2bs(W1[k * 256 + n]); }
  if (i < 256 * 256){ int n = (int)i >> 8, k = (int)i & 255; W2t[i]  = f2bs(W2[k * 256 + n]); }
  if (i < 128 * 256){ int n = (int)i >> 8, k = (int)i & 255; Wg1t[i] = f2bs(Wg1[k * 128 + n]); }
  if (i < (size_t)NN * IN_C / 4){
    const float4 v = ((const float4*)x)[i];
    ushort4 o;
    o.x = f2bs(v.x); o.y = f2bs(v.y); o.z = f2bs(v.z); o.w = f2bs(v.w);
    ((ushort4*)xb)[i] = o;
  }
  if (i < (size_t)NN * IN_C) agg[i] = 0.f;
  if (i < NV) cnt[i] = 0;
  if (i < 256) aux[i] = 0;
}

// ---------------- counting sort by dst: hist -> scan -> scatter ----------
__global__ __launch_bounds__(256) void k_hist(const int* __restrict__ ei,
                                              int* __restrict__ cnt){
  int e = blockIdx.x * 256 + threadIdx.x;
  if (e < EE) atomicAdd(&cnt[ei[EE + e]], 1);
}

// scan1: block-local exclusive prefix into off; re-zero cnt (becomes fill)
__global__ __launch_bounds__(256) void k_scan1(int* __restrict__ cnt,
                                               int* __restrict__ off,
                                               int* __restrict__ aux){
  __shared__ int s[256];
  int t = threadIdx.x, i = blockIdx.x * 256 + t;
  int val = cnt[i];
  s[t] = val; __syncthreads();
#pragma unroll
  for (int o = 1; o < 256; o <<= 1){
    int v = (t >= o) ? s[t - o] : 0;
    __syncthreads();
    s[t] += v;
    __syncthreads();
  }
  off[i] = s[t] - val;
  cnt[i] = 0;                                // reuse as fill
  if (t == 255) aux[blockIdx.x] = s[255];
}

__global__ __launch_bounds__(256) void k_scan2(int* __restrict__ aux){
  __shared__ int s[256];
  int t = threadIdx.x;
  int val = aux[t];
  s[t] = val; __syncthreads();
#pragma unroll
  for (int o = 1; o < 256; o <<= 1){
    int v = (t >= o) ? s[t - o] : 0;
    __syncthreads();
    s[t] += v;
    __syncthreads();
  }
  aux[t] = s[t] - val;
}

// scatter: global off = off[d] + aux[d>>8]; fill = cnt (zeroed by scan1)
__global__ __launch_bounds__(256) void k_scatter(const int* __restrict__ ei,
                                                 const int* __restrict__ off,
                                                 const int* __restrict__ aux,
                                                 int* __restrict__ fill,
                                                 uint4* __restrict__ sorted){
  int e = blockIdx.x * 256 + threadIdx.x;
  if (e < EE){
    int s = ei[e], d = ei[EE + e];
    int pos = off[d] + aux[d >> 8] + atomicAdd(&fill[d], 1);
    sorted[pos] = make_uint4((unsigned)e, (unsigned)s, (unsigned)d, 0u);
  }
}

// ---------------- edge stage (unchanged from R10/R11) --------------------
__global__ __launch_bounds__(256, 4) void k_edge2(
    const unsigned short* __restrict__ xb, const uint4* __restrict__ sorted,
    const float* __restrict__ edge_attr,
    const unsigned short* __restrict__ Wet, const float* __restrict__ be,
    float* __restrict__ agg)
{
  __shared__ float msgS[64 * 132];
  __shared__ uint4 sE[64];
  __shared__ int runStart[66];
  __shared__ int nRunsS;
  unsigned short* eaS = (unsigned short*)msgS;

  const int tid = threadIdx.x;
  const int e0 = blockIdx.x * 64;
  if (tid < 64) sE[tid] = sorted[e0 + tid];
  __syncthreads();

  const int lane = tid & 63, wv = tid >> 6;
  const int q = lane >> 4, l15 = lane & 15;
  const int g0 = wv * 16;

  const int xrow = g0 + (lane >> 2);
  const int xc0 = (lane & 3) * 32;
  const unsigned short* xptr = xb + (size_t)((int)sE[xrow].y) * IN_C + xc0;
  uint4 xr[4];
#pragma unroll
  for (int j = 0; j < 4; ++j) xr[j] = *(const uint4*)(xptr + j * 8);

#pragma unroll
  for (int t = 0; t < 4; ++t){
    int f4 = t * 256 + tid;
    int er = f4 >> 4;
    int kk = (f4 & 15) * 4;
    int eid = (int)sE[er].x;
    const float4 v = *(const float4*)(edge_attr + (size_t)eid * ED_C + kk);
    unsigned p0 = (unsigned)f2bs(v.x) | ((unsigned)f2bs(v.y) << 16);
    unsigned p1 = (unsigned)f2bs(v.z) | ((unsigned)f2bs(v.w) << 16);
    *(uint2*)&eaS[er * 72 + kk] = make_uint2(p0, p1);
  }

  if (tid < 64){
    bool flag = (tid == 0) || ((int)sE[tid].z != (int)sE[tid - 1].z);
    unsigned long long m = __ballot(flag);
    int pre = __popcll(m & ((1ull << tid) - 1ull));
    if ((m >> tid) & 1ull) runStart[pre] = tid;
    if (tid == 0){
      int nr = __popcll(m);
      nRunsS = nr;
      runStart[nr] = 64;
    }
  }
  __syncthreads();

  f4acc acc[8];
  const f4acc zz = {0.f, 0.f, 0.f, 0.f};
#pragma unroll
  for (int nt = 0; nt < 8; ++nt) acc[nt] = zz;

#pragma unroll
  for (int ks = 0; ks < 2; ++ks){
    bfrag a = *(const bfrag*)&eaS[(g0 + l15) * 72 + ks * 32 + q * 8];
#pragma unroll
    for (int nt = 0; nt < 8; ++nt){
      int c = nt * 16 + l15;
      bfrag b = *(const bfrag*)(Wet + c * ED_C + ks * 32 + q * 8);
      acc[nt] = __builtin_amdgcn_mfma_f32_16x16x32_bf16(a, b, acc[nt], 0, 0, 0);
    }
  }

  float bev[8];
#pragma unroll
  for (int nt = 0; nt < 8; ++nt) bev[nt] = be[nt * 16 + l15];

  __syncthreads();

#pragma unroll
  for (int nt = 0; nt < 8; ++nt){
    int c = nt * 16 + l15;
#pragma unroll
    for (int r = 0; r < 4; ++r)
      msgS[(g0 + q * 4 + r) * 132 + c] = acc[nt][r] + bev[nt];
  }

  {
    float* mr = &msgS[xrow * 132 + xc0];
#pragma unroll
    for (int jj = 0; jj < 4; ++jj){
      const uint4 u = xr[jj];
      float4 w0 = *(float4*)(mr + jj * 8);
      float4 w1 = *(float4*)(mr + jj * 8 + 4);
      w0.x = fmaxf(w0.x + __uint_as_float(u.x << 16), 0.f);
      w0.y = fmaxf(w0.y + __uint_as_float(u.x & 0xffff0000u), 0.f);
      w0.z = fmaxf(w0.z + __uint_as_float(u.y << 16), 0.f);
      w0.w = fmaxf(w0.w + __uint_as_float(u.y & 0xffff0000u), 0.f);
      w1.x = fmaxf(w1.x + __uint_as_float(u.z << 16), 0.f);
      w1.y = fmaxf(w1.y + __uint_as_float(u.z & 0xffff0000u), 0.f);
      w1.z = fmaxf(w1.z + __uint_as_float(u.w << 16), 0.f);
      w1.w = fmaxf(w1.w + __uint_as_float(u.w & 0xffff0000u), 0.f);
      *(float4*)(mr + jj * 8) = w0;
      *(float4*)(mr + jj * 8 + 4) = w1;
    }
  }
  __syncthreads();

  {
    const int col = tid & 127;
    const int h = tid >> 7;
    const int nR = nRunsS;
    for (int i = h; i < nR; i += 2){
      int s = runStart[i], e = runStart[i + 1];
      int dst = (int)sE[s].z;
      float run = 0.f;
      for (int r = s; r < e; ++r) run += msgS[r * 132 + col];
      size_t a = (size_t)dst * IN_C + col;
      if (s == 0 || e == 64) atomicAdd(&agg[a], run);
      else                   agg[a] = run;
    }
  }
}

// ---------------- MFMA GEMM with LDS-staged fragments --------------------
// AF: A staged as f2bs(aggA+xA) from f32 (h0 fusion). GATE: fused gate head.
template<int K, bool RELU, bool OB16, bool GATE, bool AF>
__global__ __launch_bounds__(256) void k_gemm(
    const unsigned short* __restrict__ A,
    const float* __restrict__ aggA, const float* __restrict__ xA,
    const unsigned short* __restrict__ Wt,
    const float* __restrict__ bias, unsigned short* __restrict__ outb,
    int M, int Ntot,
    const float* __restrict__ Wg2, const float* __restrict__ bg2,
    float* __restrict__ gateOut)
{
  __shared__ unsigned short aS[64 * 40];
  __shared__ unsigned short bS[128 * 40];
  __shared__ float gred[2][64];
  const int tid = threadIdx.x;
  const int lane = tid & 63, wv = tid >> 6;
  const int wi = wv >> 1, wj = wv & 1;
  const int q = lane >> 4, l15 = lane & 15;
  const int mb0 = blockIdx.x * 64;
  const int nb0 = blockIdx.y * 128;
  const int arow = tid >> 2, achk = tid & 3;

  f4acc acc[2][4];
  const f4acc zz = {0.f, 0.f, 0.f, 0.f};
#pragma unroll
  for (int mt = 0; mt < 2; ++mt)
#pragma unroll
    for (int nt = 0; nt < 4; ++nt) acc[mt][nt] = zz;

  for (int ks = 0; ks < K / 32; ++ks){
    {
      int m = mb0 + arow; if (m >= M) m = M - 1;
      if (AF){
        size_t base = (size_t)m * K + ks * 32 + achk * 8;
        const float4 a0 = *(const float4*)(aggA + base);
        const float4 a1 = *(const float4*)(aggA + base + 4);
        const float4 x0 = *(const float4*)(xA + base);
        const float4 x1 = *(const float4*)(xA + base + 4);
        ushort4 o0, o1;
        o0.x = f2bs(a0.x + x0.x); o0.y = f2bs(a0.y + x0.y);
        o0.z = f2bs(a0.z + x0.z); o0.w = f2bs(a0.w + x0.w);
        o1.x = f2bs(a1.x + x1.x); o1.y = f2bs(a1.y + x1.y);
        o1.z = f2bs(a1.z + x1.z); o1.w = f2bs(a1.w + x1.w);
        *(ushort4*)&aS[arow * 40 + achk * 8] = o0;
        *(ushort4*)&aS[arow * 40 + achk * 8 + 4] = o1;
      } else {
        const uint4 v = *(const uint4*)(A + (size_t)m * K + ks * 32 + achk * 8);
        *(uint4*)&aS[arow * 40 + achk * 8] = v;
      }
    }
#pragma unroll
    for (int i = 0; i < 2; ++i){
      int idx = i * 256 + tid;
      int row = idx >> 2, chk = idx & 3;
      const uint4 v = *(const uint4*)(Wt + (size_t)(nb0 + row) * K + ks * 32 + chk * 8);
      *(uint4*)&bS[row * 40 + chk * 8] = v;
    }
    __syncthreads();
    bfrag a[2], b[4];
#pragma unroll
    for (int mt = 0; mt < 2; ++mt)
      a[mt] = *(const bfrag*)&aS[(wi * 32 + mt * 16 + l15) * 40 + q * 8];
#pragma unroll
    for (int nt = 0; nt < 4; ++nt)
      b[nt] = *(const bfrag*)&bS[(wj * 64 + nt * 16 + l15) * 40 + q * 8];
#pragma unroll
    for (int mt = 0; mt < 2; ++mt)
#pragma unroll
      for (int nt = 0; nt < 4; ++nt)
        acc[mt][nt] = __builtin_amdgcn_mfma_f32_16x16x32_bf16(a[mt], b[nt], acc[mt][nt], 0, 0, 0);
    __syncthreads();
  }

  const int mb = mb0 + wi * 32;
  const int nb = nb0 + wj * 64;

  if (GATE){
    float wg2v[4];
#pragma unroll
    for (int nt = 0; nt < 4; ++nt) wg2v[nt] = Wg2[wj * 64 + nt * 16 + l15];
    float pr[2][4];
#pragma unroll
    for (int mt = 0; mt < 2; ++mt)
#pragma unroll
      for (int r = 0; r < 4; ++r) pr[mt][r] = 0.f;
#pragma unroll
    for (int nt = 0; nt < 4; ++nt){
      float bv = bias[wj * 64 + nt * 16 + l15];
#pragma unroll
      for (int mt = 0; mt < 2; ++mt)
#pragma unroll
        for (int r = 0; r < 4; ++r){
          float v = acc[mt][nt][r] + bv;
          v = v > 0.f ? v : 0.f;
          pr[mt][r] = fmaf(v, wg2v[nt], pr[mt][r]);
        }
    }
#pragma unroll
    for (int off = 1; off < 16; off <<= 1)
#pragma unroll
      for (int mt = 0; mt < 2; ++mt)
#pragma unroll
        for (int r = 0; r < 4; ++r)
          pr[mt][r] += __shfl_xor(pr[mt][r], off);
    if (l15 == 0){
#pragma unroll
      for (int mt = 0; mt < 2; ++mt)
#pragma unroll
        for (int r = 0; r < 4; ++r)
          gred[wj][wi * 32 + mt * 16 + q * 4 + r] = pr[mt][r];
    }
    __syncthreads();
    if (tid < 64){
      int m = mb0 + tid;
      if (m < M) gateOut[m] = gred[0][tid] + gred[1][tid] + bg2[0];
    }
  } else {
#pragma unroll
    for (int nt = 0; nt < 4; ++nt){
      int c = nb + nt * 16 + l15;
      float bv = bias[c];
#pragma unroll
      for (int mt = 0; mt < 2; ++mt){
#pragma unroll
        for (int r = 0; r < 4; ++r){
          int m = mb + mt * 16 + q * 4 + r;
          if (m < M){
            float v = acc[mt][nt][r] + bv;
            if (RELU) v = v > 0.f ? v : 0.f;
            if (OB16) outb[(size_t)m * Ntot + c] = f2bs(v);
          }
        }
      }
    }
  }
}

// -------- attn: segment softmax + pooled + head, 1 block per graph -------
__global__ __launch_bounds__(256) void k_attn(
    const float* __restrict__ gate, const int* __restrict__ batch,
    const unsigned short* __restrict__ h2b,
    const float* __restrict__ Wh, const float* __restrict__ bh, int nrows,
    float* __restrict__ out_logits, float* __restrict__ out_pooled)
{
  __shared__ float red[256];
  __shared__ int seg[2];
  __shared__ float pS[HID_C];
  const int b = blockIdx.x, t = threadIdx.x;

  if (t == 0){
    int lo = 0, hi = nrows;
    while (lo < hi){ int mid = (lo + hi) >> 1; if (batch[mid] < b) lo = mid + 1; else hi = mid; }
    seg[0] = lo;
    int lo2 = lo, hi2 = nrows;
    while (lo2 < hi2){ int mid = (lo2 + hi2) >> 1; if (batch[mid] < b + 1) lo2 = mid + 1; else hi2 = mid; }
    seg[1] = lo2;
  }
  __syncthreads();
  const int lo = seg[0], hi = seg[1];

  // pass1: segment max
  float m = -3e38f;
  for (int n = lo + t; n < hi; n += 256) m = fmaxf(m, gate[n]);
  red[t] = m; __syncthreads();
  for (int s = 128; s > 0; s >>= 1){
    if (t < s) red[t] = fmaxf(red[t], red[t + s]);
    __syncthreads();
  }
  m = red[0]; __syncthreads();

  // pass2: denom
  float dsum = 0.f;
  for (int n = lo + t; n < hi; n += 256) dsum += expf(gate[n] - m);
  red[t] = dsum; __syncthreads();
  for (int s = 128; s > 0; s >>= 1){
    if (t < s) red[t] += red[t + s];
    __syncthreads();
  }
  const float invd = (hi > lo) ? 1.f / red[0] : 0.f;

  // pass3: pooled[b][t] = sum_n w_n * h2[n][t]
  float acc = 0.f;
  for (int n = lo; n < hi; ++n){
    float w = expf(gate[n] - m) * invd;
    acc = fmaf(w, bs2f(h2b[(size_t)n * HID_C + t]), acc);
  }
  out_pooled[(size_t)b * HID_C + t] = acc;
  pS[t] = acc;
  __syncthreads();

  // head: logits[b][c] = pS . Wh[:,c] + bh[c]
  for (int c = t; c < KK; c += 256){
    float a2 = bh[c];
#pragma unroll 8
    for (int k = 0; k < HID_C; ++k)
      a2 = fmaf(pS[k], Wh[k * KK + c], a2);
    out_logits[(size_t)b * KK + c] = a2;
  }
}

extern "C" void kernel_launch(void* const* d_in, const int* in_sizes, int n_in,
                              void* d_out, int out_size, void* d_ws, size_t ws_size,
                              hipStream_t stream) {
  const float* x   = (const float*)d_in[0];
  const int*   ei  = (const int*)d_in[1];
  const float* ea  = (const float*)d_in[2];
  const int*   batch = (const int*)d_in[3];
  const float* We  = (const float*)d_in[4];
  const float* be  = (const float*)d_in[5];
  const float* W1  = (const float*)d_in[6];
  const float* b1  = (const float*)d_in[7];
  const float* W2  = (const float*)d_in[8];
  const float* b2  = (const float*)d_in[9];
  const float* Wg1 = (const float*)d_in[10];
  const float* bg1 = (const float*)d_in[11];
  const float* Wg2 = (const float*)d_in[12];
  const float* bg2 = (const float*)d_in[13];
  const float* Wh  = (const float*)d_in[14];
  const float* bh  = (const float*)d_in[15];

  float* out_logits = (float*)d_out;
  float* out_pooled = out_logits + (size_t)BB * KK;

  // ws layout: agg | gate | h1b (aliased by sort scratch) | h2b | weights | xb
  float* agg  = (float*)d_ws;                      // N*128 f32
  float* gate = agg + (size_t)NN * IN_C;           // N
  float* fend = gate + NN;                         // 16B-aligned (N*4 = 200KB)
  unsigned short* h1b  = (unsigned short*)fend;    // N*256 bf16 (25.6MB)
  unsigned short* h2b  = h1b + (size_t)NN * HID_C; // N*256 bf16
  unsigned short* Wet  = h2b + (size_t)NN * HID_C; // 128*64
  unsigned short* W1t  = Wet + 128 * 64;
  unsigned short* W2t  = W1t + 256 * 128;
  unsigned short* Wg1t = W2t + 256 * 256;
  unsigned short* xb   = Wg1t + 128 * 256;         // N*128 bf16 (12.8MB)
  // sort scratch aliases h1b region (dead until gemm1): 12.8+0.5MB < 25.6MB
  uint4* sorted = (uint4*)h1b;                     // EE * 16B
  int* cnt  = (int*)(sorted + EE);                 // NV (doubles as fill)
  int* off  = cnt + NV;                            // NV
  int* aux  = off + NV;                            // 256

  k_setup<<<(NN * IN_C + 255) / 256, 256, 0, stream>>>(
      We, W1, W2, Wg1, x, Wet, W1t, W2t, Wg1t, xb, agg, cnt, aux);
  // counting sort by dst (scan3 folded into scatter; cnt reused as fill)
  k_hist   <<<(EE + 255) / 256, 256, 0, stream>>>(ei, cnt);
  k_scan1  <<<NV / 256, 256, 0, stream>>>(cnt, off, aux);
  k_scan2  <<<1, 256, 0, stream>>>(aux);
  k_scatter<<<(EE + 255) / 256, 256, 0, stream>>>(ei, off, aux, cnt, sorted);
  // edge projection + message + run-list segmented-reduce scatter
  k_edge2<<<EE / 64, 256, 0, stream>>>(xb, sorted, ea, Wet, be, agg);
  // gemm1 fused with h0 (A = f2bs(agg+x)); gemm2; gemm3+gate fused
  k_gemm<128, true,  true,  false, true ><<<dim3(782, 2), 256, 0, stream>>>(
      (const unsigned short*)0, agg, x, W1t, b1, h1b, NN, HID_C,
      (const float*)0, (const float*)0, (float*)0);
  k_gemm<256, false, true,  false, false><<<dim3(782, 2), 256, 0, stream>>>(
      h1b, (const float*)0, (const float*)0, W2t, b2, h2b, NN, HID_C,
      (const float*)0, (const float*)0, (float*)0);
  k_gemm<256, true,  false, true,  false><<<dim3(782, 1), 256, 0, stream>>>(
      h2b, (const float*)0, (const float*)0, Wg1t, bg1, (unsigned short*)0, NN, G1_C,
      Wg2, bg2, gate);
  // fused segment-softmax + pool + head
  k_attn<<<BB, 256, 0, stream>>>(gate, batch, h2b, Wh, bh, NN,
                                 out_logits, out_pooled);
}

// Round 11
// 634.325 us; speedup vs baseline: 1.1381x; 1.1381x over previous
//
#include <hip/hip_runtime.h>
#include <stdint.h>

// Problem constants
#define NN    50000
#define EE    800000
#define IN_C  128
#define ED_C  64
#define HID_C 256
#define BB    128
#define KK    1000
#define G1_C  128
#define NV    50176   // NN padded to 196*256 for scan
#define EG    512     // persistent edge grid (2 blocks/CU)

// R6-R10: edge ~160us floor; byte-slope ~5TB/s + fixed ~120us latency term.
// R12: launch-fusion theory falsified (-5 launches => +55us; AF-gemm1 read
// 4x f32, k_attn 0.5 blk/CU). R13 (this): revert to R11 pipeline; make
// k_edge2 PERSISTENT + software-pipelined (T14 split: issue loads ->
// compute -> raw s_barrier(lgkm only) -> walk -> convert+LDS write ->
// raw barrier). Loads stay in flight across barriers (no vmcnt(0) drain).
// sorted packed uint2 (e | s|d<<16). Wet/be hoisted to regs.

typedef __attribute__((ext_vector_type(8))) short bfrag;   // 8 x bf16
typedef __attribute__((ext_vector_type(4))) float f4acc;   // 4 x f32 acc

__device__ __forceinline__ unsigned short f2bs(float f){   // f32 -> bf16 (RNE)
  unsigned u = __float_as_uint(f);
  return (unsigned short)((u + 0x7fffu + ((u >> 16) & 1u)) >> 16);
}
__device__ __forceinline__ float bs2f(unsigned short s){
  return __uint_as_float(((unsigned)s) << 16);
}

__device__ __forceinline__ void atomicMaxFloat(float* addr, float val){
  int old = __float_as_int(*addr);
  while (__int_as_float(old) < val){
    int assumed = old;
    old = atomicCAS((int*)addr, assumed, __float_as_int(val));
    if (old == assumed) break;
  }
}

// ------- setup: weights->bf16t, x->bf16, zero agg/cnt/aux, init B-bufs ---
__global__ __launch_bounds__(256) void k_setup(
    const float* __restrict__ We, const float* __restrict__ W1,
    const float* __restrict__ W2, const float* __restrict__ Wg1,
    const float* __restrict__ x,
    unsigned short* __restrict__ Wet, unsigned short* __restrict__ W1t,
    unsigned short* __restrict__ W2t, unsigned short* __restrict__ Wg1t,
    unsigned short* __restrict__ xb,
    float* __restrict__ agg, int* __restrict__ cnt, int* __restrict__ aux,
    float* __restrict__ gmax, float* __restrict__ denom,
    float* __restrict__ pooled)
{
  size_t i = (size_t)blockIdx.x * 256 + threadIdx.x;
  if (i < 128 * 64){ int c = (int)i >> 6, k = (int)i & 63;  Wet[i]  = f2bs(We[k * 128 + c]); }
  if (i < 256 * 128){ int n = (int)i >> 7, k = (int)i & 127; W1t[i]  = f2bs(W1[k * 256 + n]); }
  if (i < 256 * 256){ int n = (int)i >> 8, k = (int)i & 255; W2t[i]  = f2bs(W2[k * 256 + n]); }
  if (i < 128 * 256){ int n = (int)i >> 8, k = (int)i & 255; Wg1t[i] = f2bs(Wg1[k * 128 + n]); }
  if (i < (size_t)NN * IN_C / 4){
    const float4 v = ((const float4*)x)[i];
    ushort4 o;
    o.x = f2bs(v.x); o.y = f2bs(v.y); o.z = f2bs(v.z); o.w = f2bs(v.w);
    ((ushort4*)xb)[i] = o;
  }
  if (i < (size_t)NN * IN_C) agg[i] = 0.f;
  if (i < NV) cnt[i] = 0;
  if (i < 256) aux[i] = 0;
  if (i < BB){ gmax[i] = -1e30f; denom[i] = 0.f; }
  if (i < BB * HID_C) pooled[i] = 0.f;
}

// ---------------- counting sort by dst: hist -> scan -> scatter ----------
__global__ __launch_bounds__(256) void k_hist(const int* __restrict__ ei,
                                              int* __restrict__ cnt){
  int e = blockIdx.x * 256 + threadIdx.x;
  if (e < EE) atomicAdd(&cnt[ei[EE + e]], 1);
}

// scan1: block-local exclusive prefix into off; re-zero cnt (becomes fill)
__global__ __launch_bounds__(256) void k_scan1(int* __restrict__ cnt,
                                               int* __restrict__ off,
                                               int* __restrict__ aux){
  __shared__ int s[256];
  int t = threadIdx.x, i = blockIdx.x * 256 + t;
  int val = cnt[i];
  s[t] = val; __syncthreads();
#pragma unroll
  for (int o = 1; o < 256; o <<= 1){
    int v = (t >= o) ? s[t - o] : 0;
    __syncthreads();
    s[t] += v;
    __syncthreads();
  }
  off[i] = s[t] - val;
  cnt[i] = 0;                                // reuse as fill
  if (t == 255) aux[blockIdx.x] = s[255];
}

__global__ __launch_bounds__(256) void k_scan2(int* __restrict__ aux){
  __shared__ int s[256];
  int t = threadIdx.x;
  int val = aux[t];
  s[t] = val; __syncthreads();
#pragma unroll
  for (int o = 1; o < 256; o <<= 1){
    int v = (t >= o) ? s[t - o] : 0;
    __syncthreads();
    s[t] += v;
    __syncthreads();
  }
  aux[t] = s[t] - val;
}

// scatter: packed uint2 record {e, s | d<<16}; fill = cnt (zeroed by scan1)
__global__ __launch_bounds__(256) void k_scatter(const int* __restrict__ ei,
                                                 const int* __restrict__ off,
                                                 const int* __restrict__ aux,
                                                 int* __restrict__ fill,
                                                 uint2* __restrict__ sorted){
  int e = blockIdx.x * 256 + threadIdx.x;
  if (e < EE){
    int s = ei[e], d = ei[EE + e];
    int pos = off[d] + aux[d >> 8] + atomicAdd(&fill[d], 1);
    sorted[pos] = make_uint2((unsigned)e, (unsigned)s | ((unsigned)d << 16));
  }
}

// ------------- persistent pipelined edge stage -------------------------
// 512 blocks x ~24 tiles. Per iter: issue loads(t+1) | MFMA+fold(t) |
// raw barrier (lgkm only; globals stay in flight) | walk(t) |
// convert+ds_write stage(t+1) | raw barrier.
__global__ __launch_bounds__(256, 2) void k_edge2(
    const unsigned short* __restrict__ xb, const uint2* __restrict__ sorted,
    const float* __restrict__ edge_attr,
    const unsigned short* __restrict__ Wet, const float* __restrict__ be,
    float* __restrict__ agg)
{
  __shared__ float msgS[64 * 132];           // 33.8KB
  __shared__ uint2 sE[3][64];                // 1.5KB (triple-buffer)
  __shared__ unsigned short eaS[2][64 * 72]; // 18.4KB (double-buffer)
  __shared__ int runStart[2][66];
  __shared__ int nRunsS[2];

  const int tid = threadIdx.x;
  const int lane = tid & 63, wv = tid >> 6;
  const int q = lane >> 4, l15 = lane & 15;
  const int g0 = wv * 16;
  const int xrow = g0 + (lane >> 2);
  const int xc0 = (lane & 3) * 32;
  const int NT = EE / 64;
  const int t0 = blockIdx.x;

  // invariant preloads (registers, reused across all tiles)
  bfrag bW[2][8];
#pragma unroll
  for (int ks = 0; ks < 2; ++ks)
#pragma unroll
    for (int nt = 0; nt < 8; ++nt)
      bW[ks][nt] = *(const bfrag*)(Wet + (size_t)(nt * 16 + l15) * ED_C + ks * 32 + q * 8);
  float bev[8];
#pragma unroll
  for (int nt = 0; nt < 8; ++nt) bev[nt] = be[nt * 16 + l15];

  // prologue: sE[0]=t0, sE[1]=t0+EG
  if (tid < 64){
    sE[0][tid] = sorted[(size_t)t0 * 64 + tid];
    if (t0 + EG < NT) sE[1][tid] = sorted[(size_t)(t0 + EG) * 64 + tid];
  }
  __syncthreads();

  uint4 xrA[4], xrB[4];
  // synchronous stage of tile t0 -> eaS[0], runStart[0], xrA
  {
#pragma unroll
    for (int tt = 0; tt < 4; ++tt){
      int f4 = tt * 256 + tid;
      int er = f4 >> 4, kk = (f4 & 15) * 4;
      int eid = (int)sE[0][er].x;
      const float4 v = *(const float4*)(edge_attr + (size_t)eid * ED_C + kk);
      unsigned p0 = (unsigned)f2bs(v.x) | ((unsigned)f2bs(v.y) << 16);
      unsigned p1 = (unsigned)f2bs(v.z) | ((unsigned)f2bs(v.w) << 16);
      *(uint2*)&eaS[0][er * 72 + kk] = make_uint2(p0, p1);
    }
    const unsigned short* xptr = xb + (size_t)(sE[0][xrow].y & 0xffffu) * IN_C + xc0;
#pragma unroll
    for (int j = 0; j < 4; ++j) xrA[j] = *(const uint4*)(xptr + j * 8);
    if (tid < 64){
      unsigned dc = sE[0][tid].y >> 16;
      bool flag = (tid == 0) || (dc != (sE[0][tid - 1].y >> 16));
      unsigned long long m = __ballot(flag);
      int pre = __popcll(m & ((1ull << tid) - 1ull));
      if ((m >> tid) & 1ull) runStart[0][pre] = tid;
      if (tid == 0){ int nr = __popcll(m); nRunsS[0] = nr; runStart[0][nr] = 64; }
    }
  }
  __syncthreads();

  auto iterbody = [&](int i, int p, uint4 (&xrC)[4], uint4 (&xrN)[4]){
    const int t = t0 + i * EG;
    const int tn = t + EG, tnn = tn + EG;
    const uint2* sEc = sE[i % 3];
    const uint2* sEn = sE[(i + 1) % 3];
    const bool hasN = tn < NT;

    // --- issue sorted prefetch (t+2EG) into regs ---
    uint2 sereg = make_uint2(0u, 0u);
    if (tid < 64 && tnn < NT) sereg = sorted[(size_t)tnn * 64 + tid];

    // --- issue stage loads for t+EG (kept in regs until after walk) ---
    float4 eL[4];
    if (hasN){
#pragma unroll
      for (int tt = 0; tt < 4; ++tt){
        int f4 = tt * 256 + tid;
        int er = f4 >> 4, kk = (f4 & 15) * 4;
        int eid = (int)sEn[er].x;
        eL[tt] = *(const float4*)(edge_attr + (size_t)eid * ED_C + kk);
      }
      const unsigned short* xptr = xb + (size_t)(sEn[xrow].y & 0xffffu) * IN_C + xc0;
#pragma unroll
      for (int j = 0; j < 4; ++j) xrN[j] = *(const uint4*)(xptr + j * 8);
    }

    // --- compute tile t: MFMA + frag-write + fold ---
    f4acc acc[8];
    const f4acc zz = {0.f, 0.f, 0.f, 0.f};
#pragma unroll
    for (int nt = 0; nt < 8; ++nt) acc[nt] = zz;
#pragma unroll
    for (int ks = 0; ks < 2; ++ks){
      bfrag a = *(const bfrag*)&eaS[p][(g0 + l15) * 72 + ks * 32 + q * 8];
#pragma unroll
      for (int nt = 0; nt < 8; ++nt)
        acc[nt] = __builtin_amdgcn_mfma_f32_16x16x32_bf16(a, bW[ks][nt], acc[nt], 0, 0, 0);
    }
#pragma unroll
    for (int nt = 0; nt < 8; ++nt){
      int c = nt * 16 + l15;
#pragma unroll
      for (int r = 0; r < 4; ++r)
        msgS[(g0 + q * 4 + r) * 132 + c] = acc[nt][r] + bev[nt];
    }
    {
      float* mr = &msgS[xrow * 132 + xc0];
#pragma unroll
      for (int jj = 0; jj < 4; ++jj){
        const uint4 u = xrC[jj];
        float4 w0 = *(float4*)(mr + jj * 8);
        float4 w1 = *(float4*)(mr + jj * 8 + 4);
        w0.x = fmaxf(w0.x + __uint_as_float(u.x << 16), 0.f);
        w0.y = fmaxf(w0.y + __uint_as_float(u.x & 0xffff0000u), 0.f);
        w0.z = fmaxf(w0.z + __uint_as_float(u.y << 16), 0.f);
        w0.w = fmaxf(w0.w + __uint_as_float(u.y & 0xffff0000u), 0.f);
        w1.x = fmaxf(w1.x + __uint_as_float(u.z << 16), 0.f);
        w1.y = fmaxf(w1.y + __uint_as_float(u.z & 0xffff0000u), 0.f);
        w1.z = fmaxf(w1.z + __uint_as_float(u.w << 16), 0.f);
        w1.w = fmaxf(w1.w + __uint_as_float(u.w & 0xffff0000u), 0.f);
        *(float4*)(mr + jj * 8) = w0;
        *(float4*)(mr + jj * 8 + 4) = w1;
      }
    }
    // barrier A: LDS-visibility only; global loads stay in flight
    asm volatile("s_waitcnt lgkmcnt(0)" ::: "memory");
    __builtin_amdgcn_s_barrier();
    __builtin_amdgcn_sched_barrier(0);

    // --- walk tile t (LDS + global stores; overlaps in-flight loads) ---
    {
      const int col = tid & 127;
      const int h = tid >> 7;
      const int nR = nRunsS[p];
      for (int i2 = h; i2 < nR; i2 += 2){
        int s = runStart[p][i2], e = runStart[p][i2 + 1];
        int dst = (int)(sEc[s].y >> 16);
        float run = 0.f;
        for (int r = s; r < e; ++r) run += msgS[r * 132 + col];
        size_t a = (size_t)dst * IN_C + col;
        if (s == 0 || e == 64) atomicAdd(&agg[a], run);
        else                   agg[a] = run;
      }
    }

    // --- stage-write t+EG (waits its own loads via reg deps) ---
    if (hasN){
#pragma unroll
      for (int tt = 0; tt < 4; ++tt){
        int f4 = tt * 256 + tid;
        int er = f4 >> 4, kk = (f4 & 15) * 4;
        unsigned p0 = (unsigned)f2bs(eL[tt].x) | ((unsigned)f2bs(eL[tt].y) << 16);
        unsigned p1 = (unsigned)f2bs(eL[tt].z) | ((unsigned)f2bs(eL[tt].w) << 16);
        *(uint2*)&eaS[p ^ 1][er * 72 + kk] = make_uint2(p0, p1);
      }
      if (tid < 64){
        unsigned dc = sEn[tid].y >> 16;
        bool flag = (tid == 0) || (dc != (sEn[tid - 1].y >> 16));
        unsigned long long m = __ballot(flag);
        int pre = __popcll(m & ((1ull << tid) - 1ull));
        if ((m >> tid) & 1ull) runStart[p ^ 1][pre] = tid;
        if (tid == 0){ int nr = __popcll(m); nRunsS[p ^ 1] = nr; runStart[p ^ 1][nr] = 64; }
      }
    }
    if (tid < 64 && tnn < NT) sE[(i + 2) % 3][tid] = sereg;

    // barrier B
    asm volatile("s_waitcnt lgkmcnt(0)" ::: "memory");
    __builtin_amdgcn_s_barrier();
    __builtin_amdgcn_sched_barrier(0);
  };

  int i = 0;
  for (;;){
    if (t0 + i * EG >= NT) break;
    iterbody(i, 0, xrA, xrB);
    ++i;
    if (t0 + i * EG >= NT) break;
    iterbody(i, 1, xrB, xrA);
    ++i;
  }
}

// ---------------- h0 = agg + x -> bf16 ----------------
__global__ __launch_bounds__(256) void k_h0(const float* __restrict__ agg,
                                            const float* __restrict__ x,
                                            unsigned short* __restrict__ h0b){
  int i = blockIdx.x * 256 + threadIdx.x;
  if (i < NN * IN_C) h0b[i] = f2bs(agg[i] + x[i]);
}

// ---------------- MFMA GEMM with LDS-staged fragments --------------------
// GATE: fused gate head -> gateOut[m] = sum_c relu(out[m][c])*Wg2[c] + bg2.
template<int K, bool RELU, bool OB16, bool GATE>
__global__ __launch_bounds__(256) void k_gemm(
    const unsigned short* __restrict__ A, const unsigned short* __restrict__ Wt,
    const float* __restrict__ bias, unsigned short* __restrict__ outb,
    int M, int Ntot,
    const float* __restrict__ Wg2, const float* __restrict__ bg2,
    float* __restrict__ gateOut)
{
  __shared__ unsigned short aS[64 * 40];
  __shared__ unsigned short bS[128 * 40];
  __shared__ float gred[2][64];
  const int tid = threadIdx.x;
  const int lane = tid & 63, wv = tid >> 6;
  const int wi = wv >> 1, wj = wv & 1;
  const int q = lane >> 4, l15 = lane & 15;
  const int mb0 = blockIdx.x * 64;
  const int nb0 = blockIdx.y * 128;
  const int arow = tid >> 2, achk = tid & 3;

  f4acc acc[2][4];
  const f4acc zz = {0.f, 0.f, 0.f, 0.f};
#pragma unroll
  for (int mt = 0; mt < 2; ++mt)
#pragma unroll
    for (int nt = 0; nt < 4; ++nt) acc[mt][nt] = zz;

  for (int ks = 0; ks < K / 32; ++ks){
    {
      int m = mb0 + arow; if (m >= M) m = M - 1;
      const uint4 v = *(const uint4*)(A + (size_t)m * K + ks * 32 + achk * 8);
      *(uint4*)&aS[arow * 40 + achk * 8] = v;
    }
#pragma unroll
    for (int i = 0; i < 2; ++i){
      int idx = i * 256 + tid;
      int row = idx >> 2, chk = idx & 3;
      const uint4 v = *(const uint4*)(Wt + (size_t)(nb0 + row) * K + ks * 32 + chk * 8);
      *(uint4*)&bS[row * 40 + chk * 8] = v;
    }
    __syncthreads();
    bfrag a[2], b[4];
#pragma unroll
    for (int mt = 0; mt < 2; ++mt)
      a[mt] = *(const bfrag*)&aS[(wi * 32 + mt * 16 + l15) * 40 + q * 8];
#pragma unroll
    for (int nt = 0; nt < 4; ++nt)
      b[nt] = *(const bfrag*)&bS[(wj * 64 + nt * 16 + l15) * 40 + q * 8];
#pragma unroll
    for (int mt = 0; mt < 2; ++mt)
#pragma unroll
      for (int nt = 0; nt < 4; ++nt)
        acc[mt][nt] = __builtin_amdgcn_mfma_f32_16x16x32_bf16(a[mt], b[nt], acc[mt][nt], 0, 0, 0);
    __syncthreads();
  }

  const int mb = mb0 + wi * 32;
  const int nb = nb0 + wj * 64;

  if (GATE){
    float wg2v[4];
#pragma unroll
    for (int nt = 0; nt < 4; ++nt) wg2v[nt] = Wg2[wj * 64 + nt * 16 + l15];
    float pr[2][4];
#pragma unroll
    for (int mt = 0; mt < 2; ++mt)
#pragma unroll
      for (int r = 0; r < 4; ++r) pr[mt][r] = 0.f;
#pragma unroll
    for (int nt = 0; nt < 4; ++nt){
      float bv = bias[wj * 64 + nt * 16 + l15];
#pragma unroll
      for (int mt = 0; mt < 2; ++mt)
#pragma unroll
        for (int r = 0; r < 4; ++r){
          float v = acc[mt][nt][r] + bv;
          v = v > 0.f ? v : 0.f;
          pr[mt][r] = fmaf(v, wg2v[nt], pr[mt][r]);
        }
    }
#pragma unroll
    for (int off = 1; off < 16; off <<= 1)
#pragma unroll
      for (int mt = 0; mt < 2; ++mt)
#pragma unroll
        for (int r = 0; r < 4; ++r)
          pr[mt][r] += __shfl_xor(pr[mt][r], off);
    if (l15 == 0){
#pragma unroll
      for (int mt = 0; mt < 2; ++mt)
#pragma unroll
        for (int r = 0; r < 4; ++r)
          gred[wj][wi * 32 + mt * 16 + q * 4 + r] = pr[mt][r];
    }
    __syncthreads();
    if (tid < 64){
      int m = mb0 + tid;
      if (m < M) gateOut[m] = gred[0][tid] + gred[1][tid] + bg2[0];
    }
  } else {
#pragma unroll
    for (int nt = 0; nt < 4; ++nt){
      int c = nb + nt * 16 + l15;
      float bv = bias[c];
#pragma unroll
      for (int mt = 0; mt < 2; ++mt){
#pragma unroll
        for (int r = 0; r < 4; ++r){
          int m = mb + mt * 16 + q * 4 + r;
          if (m < M){
            float v = acc[mt][nt][r] + bv;
            if (RELU) v = v > 0.f ? v : 0.f;
            if (OB16) outb[(size_t)m * Ntot + c] = f2bs(v);
          }
        }
      }
    }
  }
}

// ---------------- segment max (wave-shuffle) ----------------------------
__global__ __launch_bounds__(256) void k_gmax(const float* __restrict__ gate,
                                              const int* __restrict__ batch,
                                              float* __restrict__ gmax, int nrows){
  __shared__ float wred[4];
  const int tid = threadIdx.x;
  const int n0 = blockIdx.x * 256;
  const int n = n0 + tid;
  const int nlast = (n0 + 255 < nrows) ? n0 + 255 : nrows - 1;
  const int bmin = batch[n0], bmax = batch[nlast];
  const int lane = tid & 63, wv = tid >> 6;
  float val = -3e38f; int b = bmax;
  if (n < nrows){ b = batch[n]; val = gate[n]; }
  for (int bb = bmin; bb <= bmax; ++bb){
    float v = (b == bb) ? val : -3e38f;
#pragma unroll
    for (int off = 1; off < 64; off <<= 1) v = fmaxf(v, __shfl_xor(v, off));
    if (lane == 0) wred[wv] = v;
    __syncthreads();
    if (tid == 0){
      float m = fmaxf(fmaxf(wred[0], wred[1]), fmaxf(wred[2], wred[3]));
      if (m > -1e37f) atomicMaxFloat(&gmax[bb], m);
    }
    __syncthreads();
  }
}

// ---------------- a = exp(gate - gmax[b]); denom[b] += a ----------------
__global__ __launch_bounds__(256) void k_expsum(const float* __restrict__ gate,
                                                const int* __restrict__ batch,
                                                const float* __restrict__ gmax,
                                                float* __restrict__ aexp,
                                                float* __restrict__ denom, int nrows){
  __shared__ float wred[4];
  const int tid = threadIdx.x;
  const int n0 = blockIdx.x * 256;
  const int n = n0 + tid;
  const int nlast = (n0 + 255 < nrows) ? n0 + 255 : nrows - 1;
  const int bmin = batch[n0], bmax = batch[nlast];
  const int lane = tid & 63, wv = tid >> 6;
  float val = 0.f; int b = bmax;
  if (n < nrows){
    b = batch[n];
    val = expf(gate[n] - gmax[b]);
    aexp[n] = val;
  }
  for (int bb = bmin; bb <= bmax; ++bb){
    float v = (b == bb) ? val : 0.f;
#pragma unroll
    for (int off = 1; off < 64; off <<= 1) v += __shfl_xor(v, off);
    if (lane == 0) wred[wv] = v;
    __syncthreads();
    if (tid == 0){
      float s = wred[0] + wred[1] + wred[2] + wred[3];
      if (s != 0.f) atomicAdd(&denom[bb], s);
    }
    __syncthreads();
  }
}

// ---------------- pooled[b] += (a/denom[b]) * h2[n]  (32-row chunks) -----
__global__ __launch_bounds__(256) void k_pool(const unsigned short* __restrict__ h2b,
                                              const float* __restrict__ aexp,
                                              const float* __restrict__ denom,
                                              const int* __restrict__ batch,
                                              float* __restrict__ pooled, int nrows){
  const int c = threadIdx.x;
  const int n0 = blockIdx.x * 32;
  int n1 = n0 + 32; if (n1 > nrows) n1 = nrows;
  if (n0 >= nrows) return;
  float acc = 0.f;
  int curb = batch[n0];
  for (int n = n0; n < n1; ++n){
    int b = batch[n];
    if (b != curb){
      atomicAdd(&pooled[(size_t)curb * HID_C + c], acc);
      acc = 0.f; curb = b;
    }
    float wgt = aexp[n] / denom[b];
    acc = fmaf(wgt, bs2f(h2b[(size_t)n * HID_C + c]), acc);
  }
  atomicAdd(&pooled[(size_t)curb * HID_C + c], acc);
}

// ---------------- head: logits = pooled @ Wh + bh ----------------
__global__ __launch_bounds__(256) void k_head(const float* __restrict__ pooled,
                                              const float* __restrict__ Wh,
                                              const float* __restrict__ bh,
                                              float* __restrict__ out_logits,
                                              float* __restrict__ out_pooled){
  __shared__ float p[HID_C];
  const int b = blockIdx.x, t = threadIdx.x;
  float pv = pooled[(size_t)b * HID_C + t];
  p[t] = pv;
  out_pooled[(size_t)b * HID_C + t] = pv;
  __syncthreads();
  for (int c = t; c < KK; c += 256){
    float acc = bh[c];
#pragma unroll 8
    for (int k = 0; k < HID_C; ++k)
      acc = fmaf(p[k], Wh[k * KK + c], acc);
    out_logits[(size_t)b * KK + c] = acc;
  }
}

extern "C" void kernel_launch(void* const* d_in, const int* in_sizes, int n_in,
                              void* d_out, int out_size, void* d_ws, size_t ws_size,
                              hipStream_t stream) {
  const float* x   = (const float*)d_in[0];
  const int*   ei  = (const int*)d_in[1];
  const float* ea  = (const float*)d_in[2];
  const int*   batch = (const int*)d_in[3];
  const float* We  = (const float*)d_in[4];
  const float* be  = (const float*)d_in[5];
  const float* W1  = (const float*)d_in[6];
  const float* b1  = (const float*)d_in[7];
  const float* W2  = (const float*)d_in[8];
  const float* b2  = (const float*)d_in[9];
  const float* Wg1 = (const float*)d_in[10];
  const float* bg1 = (const float*)d_in[11];
  const float* Wg2 = (const float*)d_in[12];
  const float* bg2 = (const float*)d_in[13];
  const float* Wh  = (const float*)d_in[14];
  const float* bh  = (const float*)d_in[15];

  float* out_logits = (float*)d_out;
  float* out_pooled = out_logits + (size_t)BB * KK;

  // ws layout (R11-style): f32 region | h0b | h1b (sort scratch alias) |
  // h2b | weights | xb
  float* agg    = (float*)d_ws;                    // N*128
  float* gate   = agg   + (size_t)NN * IN_C;       // N
  float* aexp   = gate  + NN;                      // N
  float* gmax   = aexp  + NN;                      // B
  float* denom  = gmax  + BB;                      // B
  float* pooled = denom + BB;                      // B*256
  float* fend   = pooled + (size_t)BB * HID_C;
  unsigned short* h0b  = (unsigned short*)fend;    // N*128 bf16
  unsigned short* h1b  = h0b + (size_t)NN * IN_C;  // N*256 bf16 (25.6MB)
  unsigned short* h2b  = h1b + (size_t)NN * HID_C; // N*256 bf16
  unsigned short* Wet  = h2b + (size_t)NN * HID_C;
  unsigned short* W1t  = Wet + 128 * 64;
  unsigned short* W2t  = W1t + 256 * 128;
  unsigned short* Wg1t = W2t + 256 * 256;
  unsigned short* xb   = Wg1t + 128 * 256;         // N*128 bf16 (12.8MB)
  // sort scratch aliases h1b region (dead until gemm1): 6.4+0.4MB < 25.6MB
  uint2* sorted = (uint2*)h1b;                     // EE * 8B (packed)
  int* cnt  = (int*)(sorted + EE);                 // NV (doubles as fill)
  int* off  = cnt + NV;                            // NV
  int* aux  = off + NV;                            // 256

  k_setup<<<(NN * IN_C + 255) / 256, 256, 0, stream>>>(
      We, W1, W2, Wg1, x, Wet, W1t, W2t, Wg1t, xb,
      agg, cnt, aux, gmax, denom, pooled);
  // counting sort by dst
  k_hist   <<<(EE + 255) / 256, 256, 0, stream>>>(ei, cnt);
  k_scan1  <<<NV / 256, 256, 0, stream>>>(cnt, off, aux);
  k_scan2  <<<1, 256, 0, stream>>>(aux);
  k_scatter<<<(EE + 255) / 256, 256, 0, stream>>>(ei, off, aux, cnt, sorted);
  // persistent pipelined edge stage
  k_edge2<<<EG, 256, 0, stream>>>(xb, sorted, ea, Wet, be, agg);
  k_h0<<<(NN * IN_C + 255) / 256, 256, 0, stream>>>(agg, x, h0b);
  // MLP GEMMs + fused gate
  k_gemm<128, true,  true,  false><<<dim3(782, 2), 256, 0, stream>>>(
      h0b, W1t, b1, h1b, NN, HID_C, (const float*)0, (const float*)0, (float*)0);
  k_gemm<256, false, true,  false><<<dim3(782, 2), 256, 0, stream>>>(
      h1b, W2t, b2, h2b, NN, HID_C, (const float*)0, (const float*)0, (float*)0);
  k_gemm<256, true,  false, true ><<<dim3(782, 1), 256, 0, stream>>>(
      h2b, Wg1t, bg1, (unsigned short*)0, NN, G1_C, Wg2, bg2, gate);
  k_gmax  <<<(NN + 255) / 256, 256, 0, stream>>>(gate, batch, gmax, NN);
  k_expsum<<<(NN + 255) / 256, 256, 0, stream>>>(gate, batch, gmax, aexp, denom, NN);
  k_pool  <<<(NN + 31) / 32, 256, 0, stream>>>(h2b, aexp, denom, batch, pooled, NN);
  k_head<<<BB, 256, 0, stream>>>(pooled, Wh, bh, out_logits, out_pooled);
}